// Round 18
// baseline (215.903 us; speedup 1.0000x reference)
//
#include <hip/hip_runtime.h>
#include <hip/hip_bf16.h>
#include <stdint.h>

// MoTEmbed: out[t,:] = W_{type(t)} @ h[t,:] + b_{type(t)}
// B=4, S=4096 -> T=16384 tokens, D=2048. fp32 in/out, bf16 MFMA compute.
// Round 18: R17 base; dual-straddle path now TRIPLE-buffered (A/B0/B1 x3,
// 144KB) with stage-ahead-2 and vmcnt(6) counted drains (loads retired a
// full tile ~2000cyc after issue -> pre-satisfied; R17's vmcnt(0) stalled
// on ~900cyc HBM every tile). Regular path / prep / sort unchanged.

#define T_TOK 16384
#define DDIM  2048
#define NT_K  32           // K tiles of 64 (regular path)
#define NT_D  64           // K tiles of 32 (dual path)
#define MT    64           // M tiles of 256 (gap-free sort)
#define NTILE 8            // N tiles of 256

typedef __attribute__((ext_vector_type(4))) float          f32x4;
typedef __attribute__((ext_vector_type(8))) short          bf16x8;
typedef __attribute__((ext_vector_type(2))) unsigned int   u32x2;

// ---- ws layout (bytes) ----
#define WS_HBF   0ull
#define WS_W0BF  67108864ull                 // 16384*2048*2
#define WS_W1BF  75497472ull                 // + 2048*2048*2
#define WS_META  83886080ull                 // + 2048*2048*2
#define WS_IDX   83886208ull
#define WS_NEED  (WS_IDX + 65536ull)
// meta: [0]=cur0 (final = c0) [1]=cur1

__device__ __forceinline__ unsigned short cvt1_bf16(float f) {
  unsigned u = __builtin_bit_cast(unsigned, f);
  unsigned rnd = 0x7fffu + ((u >> 16) & 1u);
  return (unsigned short)((u + rnd) >> 16);
}

__device__ __forceinline__ void gload_lds16(const void* g, void* l) {
  __builtin_amdgcn_global_load_lds(
      (const __attribute__((address_space(1))) unsigned int*)g,
      (__attribute__((address_space(3))) unsigned int*)l, 16, 0, 0);
}

#define BAR()     asm volatile("s_barrier" ::: "memory")
#define VMCNT2()  asm volatile("s_waitcnt vmcnt(2)" ::: "memory")
#define VMCNT4()  asm volatile("s_waitcnt vmcnt(4)" ::: "memory")
#define VMCNT6()  asm volatile("s_waitcnt vmcnt(6)" ::: "memory")
#define VMCNT0()  asm volatile("s_waitcnt vmcnt(0)" ::: "memory")
#define LGKM0()   asm volatile("s_waitcnt lgkmcnt(0)" ::: "memory")
#define SCHEDBAR() __builtin_amdgcn_sched_barrier(0)

// ---------- prep: fused convert(H,W0,W1) + two-sided scatter ----------
__global__ void k_prep(const float* __restrict__ H, const float* __restrict__ W0,
                       const float* __restrict__ W1, const int* __restrict__ typ,
                       unsigned short* __restrict__ Hbf,
                       unsigned short* __restrict__ W0bf,
                       unsigned short* __restrict__ W1bf,
                       int* __restrict__ meta, int* __restrict__ idx) {
  const int gid = blockIdx.x * blockDim.x + threadIdx.x;
  if (gid < T_TOK) {
    int t = typ[gid];
    int pos = (t == 0) ? atomicAdd(&meta[0], 1)
                       : (T_TOK - 1) - atomicAdd(&meta[1], 1);
    idx[pos] = gid;
  }
  const int nH = T_TOK * DDIM / 4;
  const int nW = DDIM * DDIM / 4;
  const int total = nH + 2 * nW;
  const int stride = gridDim.x * blockDim.x;
  for (int i = gid; i < total; i += stride) {
    const float* s; unsigned short* d; int j;
    if (i < nH)           { s = H;  d = Hbf;  j = i; }
    else if (i < nH + nW) { s = W0; d = W0bf; j = i - nH; }
    else                  { s = W1; d = W1bf; j = i - nH - nW; }
    f32x4 v = ((const f32x4*)s)[j];
    unsigned p0 = (unsigned)cvt1_bf16(v[0]) | ((unsigned)cvt1_bf16(v[1]) << 16);
    unsigned p1 = (unsigned)cvt1_bf16(v[2]) | ((unsigned)cvt1_bf16(v[3]) << 16);
    u32x2 o; o[0] = p0; o[1] = p1;
    ((u32x2*)d)[j] = o;
  }
}

// ---------- 256x256 GEMM: R14 cadence + triple-buffered dual straddle ----------
__global__ __launch_bounds__(512) void k_gemm256(
    const unsigned short* __restrict__ Hbf,
    const unsigned short* __restrict__ W0bf,
    const unsigned short* __restrict__ W1bf,
    const float* __restrict__ B0, const float* __restrict__ B1,
    const int* __restrict__ meta, const int* __restrict__ idx,
    float* __restrict__ OUT)
{
  __shared__ char lds[147456];         // 144KB (dual: 3 x {A,B0,B1} x 16KB)

  // bijective XCD swizzle: nwg=512, chunk=64
  const int orig = blockIdx.x;
  const int wg = (orig & 7) * 64 + (orig >> 3);
  int my = wg >> 3;                    // 0..63
  const int bx = wg & 7;               // 0..7

  const int c0 = meta[0];
  int ms = c0 >> 8; if (ms > MT - 1) ms = MT - 1;
  my = (my == 0) ? ms : (my == ms) ? 0 : my;   // straddle tile first

  const int tid  = threadIdx.x;
  const int lane = tid & 63;
  const int wid  = tid >> 6;           // 0..7
  const int wr   = wid >> 2;           // 0..1 (M half)
  const int wc   = wid & 3;            // 0..3 (N quarter)
  const int fr   = lane & 15;
  const int g    = lane >> 4;

  const int start = my * 256;
  const int isDual = (start < c0 && c0 < start + 256) ? 1 : 0;
  const int e0    = (start >= c0) ? 1 : 0;
  const int colBase = bx * 256;

  // staging sources; pre-swizzled global slot (linear LDS dest)
  const int cs = (lane & 3) ^ ((lane >> 3) & 3);
  const char* aS[2];
  int rt[2];
#pragma unroll
  for (int l = 0; l < 2; ++l) {
    int ch = 2 * wid + l;
    rt[l] = ch * 16 + (lane >> 2);
    int orow = idx[start + rt[l]];
    aS[l] = (const char*)Hbf + (size_t)orow * 4096 + cs * 16;
  }
  const int chB = (2 * wid) * 1024;    // wave-uniform chunk base in a section

  // fragment byte offsets within a 256-row x 64B section (swizzled slot)
  const int sw = (g ^ ((fr >> 1) & 3)) << 4;
  int aF[8], bF[4];
#pragma unroll
  for (int m = 0; m < 8; ++m) aF[m] = ((wr * 128 + m * 16 + fr) << 6) + sw;
#pragma unroll
  for (int n = 0; n < 4; ++n) bF[n] = ((wc * 64 + n * 16 + fr) << 6) + sw;

  f32x4 acc[8][4];
#pragma unroll
  for (int m = 0; m < 8; ++m)
#pragma unroll
    for (int n = 0; n < 4; ++n) acc[m][n] = (f32x4)0.0f;

  int cols[4];
#pragma unroll
  for (int n = 0; n < 4; ++n) cols[n] = colBase + wc * 64 + n * 16 + fr;

  if (!isDual) {
    // ================= regular single-expert path (R14/R15 verified) ======
    const unsigned short* Wb = e0 ? W1bf : W0bf;
    const char* wS[2];
#pragma unroll
    for (int l = 0; l < 2; ++l)
      wS[l] = (const char*)(Wb + (size_t)(colBase + rt[l]) * DDIM) + cs * 16;

    auto STAGE_A = [&](int d, int kh, int tn) {
      char* dst = lds + (d << 15) + (kh << 14) + chB;
      int ko = tn * 128 + kh * 64;
      gload_lds16(aS[0] + ko, dst);
      gload_lds16(aS[1] + ko, dst + 1024);
    };
    auto STAGE_B = [&](int d, int kh, int tn) {
      char* dst = lds + 65536 + (d << 15) + (kh << 14) + chB;
      int ko = tn * 128 + kh * 64;
      gload_lds16(wS[0] + ko, dst);
      gload_lds16(wS[1] + ko, dst + 1024);
    };

    // prologue FIFO: Akh0(0), Bkh0(0), Akh1(0), Bkh1(0); vmcnt(4); BAR
    STAGE_A(0, 0, 0); STAGE_B(0, 0, 0); STAGE_A(0, 1, 0); STAGE_B(0, 1, 0);
    VMCNT4();
    BAR();

#pragma unroll 2
    for (int t = 0; t < NT_K; ++t) {
      const int c = t & 1, d = c ^ 1;
      int t1 = t + 1; if (t1 == NT_K) t1 = NT_K - 1;
      const char* Ak0 = lds + (c << 15);
      const char* Ak1 = Ak0 + 16384;
      const char* Bk0 = lds + 65536 + (c << 15);
      const char* Bk1 = Bk0 + 16384;

      bf16x8 a[8], bb0, bb1;

      // P1: kh0 x n0-1
#pragma unroll
      for (int m = 0; m < 8; ++m) a[m] = *(const bf16x8*)(Ak0 + aF[m]);
      bb0 = *(const bf16x8*)(Bk0 + bF[0]);
      bb1 = *(const bf16x8*)(Bk0 + bF[1]);
      STAGE_A(d, 0, t1);
      BAR(); LGKM0(); SCHEDBAR();
      __builtin_amdgcn_s_setprio(1);
#pragma unroll
      for (int m = 0; m < 8; ++m) {
        acc[m][0] = __builtin_amdgcn_mfma_f32_16x16x32_bf16(a[m], bb0, acc[m][0], 0, 0, 0);
        acc[m][1] = __builtin_amdgcn_mfma_f32_16x16x32_bf16(a[m], bb1, acc[m][1], 0, 0, 0);
      }
      __builtin_amdgcn_s_setprio(0);

      // P2: kh0 x n2-3
      bb0 = *(const bf16x8*)(Bk0 + bF[2]);
      bb1 = *(const bf16x8*)(Bk0 + bF[3]);
      VMCNT2();
      STAGE_B(d, 0, t1);
      BAR(); LGKM0(); SCHEDBAR();
      __builtin_amdgcn_s_setprio(1);
#pragma unroll
      for (int m = 0; m < 8; ++m) {
        acc[m][2] = __builtin_amdgcn_mfma_f32_16x16x32_bf16(a[m], bb0, acc[m][2], 0, 0, 0);
        acc[m][3] = __builtin_amdgcn_mfma_f32_16x16x32_bf16(a[m], bb1, acc[m][3], 0, 0, 0);
      }
      __builtin_amdgcn_s_setprio(0);

      // P3: kh1 x n0-1
#pragma unroll
      for (int m = 0; m < 8; ++m) a[m] = *(const bf16x8*)(Ak1 + aF[m]);
      bb0 = *(const bf16x8*)(Bk1 + bF[0]);
      bb1 = *(const bf16x8*)(Bk1 + bF[1]);
      STAGE_A(d, 1, t1);
      BAR(); LGKM0(); SCHEDBAR();
      __builtin_amdgcn_s_setprio(1);
#pragma unroll
      for (int m = 0; m < 8; ++m) {
        acc[m][0] = __builtin_amdgcn_mfma_f32_16x16x32_bf16(a[m], bb0, acc[m][0], 0, 0, 0);
        acc[m][1] = __builtin_amdgcn_mfma_f32_16x16x32_bf16(a[m], bb1, acc[m][1], 0, 0, 0);
      }
      __builtin_amdgcn_s_setprio(0);

      // P4: kh1 x n2-3
      bb0 = *(const bf16x8*)(Bk1 + bF[2]);
      bb1 = *(const bf16x8*)(Bk1 + bF[3]);
      VMCNT2();
      STAGE_B(d, 1, t1);
      BAR(); LGKM0(); SCHEDBAR();
      __builtin_amdgcn_s_setprio(1);
#pragma unroll
      for (int m = 0; m < 8; ++m) {
        acc[m][2] = __builtin_amdgcn_mfma_f32_16x16x32_bf16(a[m], bb0, acc[m][2], 0, 0, 0);
        acc[m][3] = __builtin_amdgcn_mfma_f32_16x16x32_bf16(a[m], bb1, acc[m][3], 0, 0, 0);
      }
      __builtin_amdgcn_s_setprio(0);
    }

    VMCNT0();

    const float* Bv = e0 ? B1 : B0;
    float bias[4];
#pragma unroll
    for (int n = 0; n < 4; ++n) bias[n] = Bv[cols[n]];
#pragma unroll
    for (int m = 0; m < 8; ++m) {
      int lb = wr * 128 + m * 16 + (g << 2);
#pragma unroll
      for (int j = 0; j < 4; ++j) {
        int orow = idx[start + lb + j];
        float* op = OUT + (size_t)orow * DDIM;
#pragma unroll
        for (int n = 0; n < 4; ++n) op[cols[n]] = acc[m][n][j] + bias[n];
      }
    }
  } else {
    // ====== dual-expert straddle: triple-buffered BK=32, stage-ahead-2 =====
    // Sections (16KB each): A(buf) @ buf*16K; B0(buf) @ 48K + buf*16K;
    // B1(buf) @ 96K + buf*16K.  Per tile t (c=t%3): reads buf c (16 b128);
    // stage S(t+2) -> buf (t+2)%3 (6 loads); vmcnt(6) retires S(t+1)
    // (issued 1 tile ~2000cyc earlier -> pre-satisfied); BAR; lgkm0; MFMA;
    // BAR.  WAR: buf (t+2)%3 = (t-1)%3, last reads lgkm-complete before
    // tile t-1's end-BAR < this stage. Visibility: each buf's retire
    // precedes >=2 barriers before its reads. Never vmcnt(0) in loop.
    const char* wS0[2]; const char* wS1[2];
#pragma unroll
    for (int l = 0; l < 2; ++l) {
      wS0[l] = (const char*)(W0bf + (size_t)(colBase + rt[l]) * DDIM) + cs * 16;
      wS1[l] = (const char*)(W1bf + (size_t)(colBase + rt[l]) * DDIM) + cs * 16;
    }
    const int lo_w = c0 - start - wr * 128;      // wave-uniform
    int mmix = 8;
    if (lo_w > 0 && lo_w < 128 && (lo_w & 15)) mmix = lo_w >> 4;

    f32x4 accX[4];
#pragma unroll
    for (int n = 0; n < 4; ++n) accX[n] = (f32x4)0.0f;

    auto DSTAGE = [&](int d, int tn) {
      int ko = tn * 64;
      char* ad  = lds + d * 16384 + chB;
      char* b0d = lds + 49152 + d * 16384 + chB;
      char* b1d = lds + 98304 + d * 16384 + chB;
      gload_lds16(aS[0] + ko, ad);
      gload_lds16(aS[1] + ko, ad + 1024);
      gload_lds16(wS0[0] + ko, b0d);
      gload_lds16(wS0[1] + ko, b0d + 1024);
      gload_lds16(wS1[0] + ko, b1d);
      gload_lds16(wS1[1] + ko, b1d + 1024);
    };

    // prologue: S0 -> buf0, S1 -> buf1; retire S0; BAR
    DSTAGE(0, 0); DSTAGE(1, 1);
    VMCNT6();
    BAR();

    for (int t = 0; t < NT_D; ++t) {
      const int c = t % 3;
      const int d = (t + 2) % 3;
      int t2 = t + 2; if (t2 >= NT_D) t2 = NT_D - 1;
      const char* Ac  = lds + c * 16384;
      const char* B0c = lds + 49152 + c * 16384;
      const char* B1c = lds + 98304 + c * 16384;
      bf16x8 a[8], b0f[4], b1f[4];
#pragma unroll
      for (int m = 0; m < 8; ++m) a[m] = *(const bf16x8*)(Ac + aF[m]);
#pragma unroll
      for (int n = 0; n < 4; ++n) {
        b0f[n] = *(const bf16x8*)(B0c + bF[n]);
        b1f[n] = *(const bf16x8*)(B1c + bF[n]);
      }
      DSTAGE(d, t2);                   // outstanding: S(t+1) 6 + S(t+2) 6
      VMCNT6();                        // retires S(t+1) -> buf(t+1) certified
      BAR(); LGKM0(); SCHEDBAR();
      __builtin_amdgcn_s_setprio(1);
#pragma unroll
      for (int m = 0; m < 8; ++m) {
        if (m == mmix) {
#pragma unroll
          for (int n = 0; n < 4; ++n) {
            acc[m][n] = __builtin_amdgcn_mfma_f32_16x16x32_bf16(a[m], b0f[n], acc[m][n], 0, 0, 0);
            accX[n]   = __builtin_amdgcn_mfma_f32_16x16x32_bf16(a[m], b1f[n], accX[n],   0, 0, 0);
          }
        } else if (m * 16 >= lo_w) {
#pragma unroll
          for (int n = 0; n < 4; ++n)
            acc[m][n] = __builtin_amdgcn_mfma_f32_16x16x32_bf16(a[m], b1f[n], acc[m][n], 0, 0, 0);
        } else {
#pragma unroll
          for (int n = 0; n < 4; ++n)
            acc[m][n] = __builtin_amdgcn_mfma_f32_16x16x32_bf16(a[m], b0f[n], acc[m][n], 0, 0, 0);
        }
      }
      __builtin_amdgcn_s_setprio(0);
      BAR();                           // all reads of buf c done -> WAR-safe
    }
    VMCNT0();

    float bias0v[4], bias1v[4];
#pragma unroll
    for (int n = 0; n < 4; ++n) { bias0v[n] = B0[cols[n]]; bias1v[n] = B1[cols[n]]; }
#pragma unroll
    for (int m = 0; m < 8; ++m) {
      int lb = wr * 128 + m * 16 + (g << 2);
      if (m == mmix) {
#pragma unroll
        for (int j = 0; j < 4; ++j) {
          int p = start + lb + j;
          int orow = idx[p];
          float* op = OUT + (size_t)orow * DDIM;
          if (p >= c0) {
#pragma unroll
            for (int n = 0; n < 4; ++n) op[cols[n]] = accX[n][j] + bias1v[n];
          } else {
#pragma unroll
            for (int n = 0; n < 4; ++n) op[cols[n]] = acc[m][n][j] + bias0v[n];
          }
        }
      } else {
        int em = (m * 16 >= lo_w) ? 1 : 0;
#pragma unroll
        for (int j = 0; j < 4; ++j) {
          int orow = idx[start + lb + j];
          float* op = OUT + (size_t)orow * DDIM;
#pragma unroll
          for (int n = 0; n < 4; ++n)
            op[cols[n]] = acc[m][n][j] + (em ? bias1v[n] : bias0v[n]);
        }
      }
    }
  }
}

// ---------- fallback: verified round-4 kernel ----------
#define BMd 64
#define BNd 64
#define BKd 32
#define LDW 36

__device__ __forceinline__ bf16x8 cvt_bf16x8(f32x4 lo, f32x4 hi) {
  bf16x8 r;
#pragma unroll
  for (int i = 0; i < 4; ++i) {
    r[i]     = (short)cvt1_bf16(lo[i]);
    r[i + 4] = (short)cvt1_bf16(hi[i]);
  }
  return r;
}

__global__ __launch_bounds__(256, 2) void mot_mfma_diag(
    const float* __restrict__ H,  const int* __restrict__ TYP,
    const float* __restrict__ W0, const float* __restrict__ B0,
    const float* __restrict__ W1, const float* __restrict__ B1,
    float* __restrict__ OUT)
{
  __shared__ float As[BMd * LDW];
  __shared__ float W0s[BNd * LDW];
  __shared__ float W1s[BNd * LDW];

  const int tid = threadIdx.x;
  const int rowBase = blockIdx.y * BMd;
  const int colBase = blockIdx.x * BNd;
  const int srow  = tid >> 3;
  const int scol4 = (tid & 7) << 2;
  const float* hA  = H  + (size_t)(rowBase + srow) * DDIM + scol4;
  const float* hW0 = W0 + (size_t)(colBase + srow) * DDIM + scol4;
  const float* hW1 = W1 + (size_t)(colBase + srow) * DDIM + scol4;

  const int lane = tid & 63;
  const int w    = tid >> 6;
  const int fr   = lane & 15;
  const int g    = lane >> 4;

  f32x4 acc0[4], acc1[4];
#pragma unroll
  for (int m = 0; m < 4; ++m) { acc0[m] = (f32x4)0.0f; acc1[m] = (f32x4)0.0f; }

  for (int k0 = 0; k0 < DDIM; k0 += BKd) {
    f32x4 va[2], v0[2], v1[2];
#pragma unroll
    for (int p = 0; p < 2; ++p) {
      va[p] = *(const f32x4*)(hA  + (size_t)p * 32 * DDIM);
      v0[p] = *(const f32x4*)(hW0 + (size_t)p * 32 * DDIM);
      v1[p] = *(const f32x4*)(hW1 + (size_t)p * 32 * DDIM);
    }
    hA += BKd; hW0 += BKd; hW1 += BKd;
    __syncthreads();
#pragma unroll
    for (int p = 0; p < 2; ++p) {
      int r = srow + 32 * p;
      *(f32x4*)(&As [r * LDW + scol4]) = va[p];
      *(f32x4*)(&W0s[r * LDW + scol4]) = v0[p];
      *(f32x4*)(&W1s[r * LDW + scol4]) = v1[p];
    }
    __syncthreads();

    bf16x8 af[4];
#pragma unroll
    for (int m = 0; m < 4; ++m) {
      const float* ap = &As[(m * 16 + fr) * LDW + g * 8];
      af[m] = cvt_bf16x8(*(const f32x4*)ap, *(const f32x4*)(ap + 4));
    }
    const float* b0p = &W0s[(w * 16 + fr) * LDW + g * 8];
    const float* b1p = &W1s[(w * 16 + fr) * LDW + g * 8];
    bf16x8 bf0 = cvt_bf16x8(*(const f32x4*)b0p, *(const f32x4*)(b0p + 4));
    bf16x8 bf1 = cvt_bf16x8(*(const f32x4*)b1p, *(const f32x4*)(b1p + 4));
#pragma unroll
    for (int m = 0; m < 4; ++m) {
      acc0[m] = __builtin_amdgcn_mfma_f32_16x16x32_bf16(af[m], bf0, acc0[m], 0, 0, 0);
      acc1[m] = __builtin_amdgcn_mfma_f32_16x16x32_bf16(af[m], bf1, acc1[m], 0, 0, 0);
    }
  }

  const int col = colBase + w * 16 + fr;
  const float bz0 = B0[col];
  const float bz1 = B1[col];
#pragma unroll
  for (int m = 0; m < 4; ++m)
#pragma unroll
    for (int j = 0; j < 4; ++j) {
      int row = rowBase + m * 16 + (g << 2) + j;
      int t = TYP[row];
      OUT[(size_t)row * DDIM + col] = (t == 0) ? (acc0[m][j] + bz0) : (acc1[m][j] + bz1);
    }
}

extern "C" void kernel_launch(void* const* d_in, const int* in_sizes, int n_in,
                              void* d_out, int out_size, void* d_ws, size_t ws_size,
                              hipStream_t stream) {
  const float* H   = (const float*)d_in[0];
  const int*   TYP = (const int*)  d_in[1];
  const float* W0  = (const float*)d_in[2];
  const float* B0v = (const float*)d_in[3];
  const float* W1  = (const float*)d_in[4];
  const float* B1v = (const float*)d_in[5];
  float* OUT = (float*)d_out;

  if (ws_size < WS_NEED) {
    dim3 grid(DDIM / BNd, T_TOK / BMd);
    mot_mfma_diag<<<grid, dim3(256), 0, stream>>>(H, TYP, W0, B0v, W1, B1v, OUT);
    return;
  }

  unsigned short* Hbf  = (unsigned short*)((char*)d_ws + WS_HBF);
  unsigned short* W0bf = (unsigned short*)((char*)d_ws + WS_W0BF);
  unsigned short* W1bf = (unsigned short*)((char*)d_ws + WS_W1BF);
  int* meta = (int*)((char*)d_ws + WS_META);
  int* idx  = (int*)((char*)d_ws + WS_IDX);

  hipMemsetAsync(meta, 0, 16, stream);
  k_prep<<<4096, 256, 0, stream>>>(H, W0, W1, TYP, Hbf, W0bf, W1bf, meta, idx);
  k_gemm256<<<MT * NTILE, 512, 0, stream>>>(Hbf, W0bf, W1bf, B0v, B1v, meta, idx, OUT);
}

// Round 19
// 210.543 us; speedup vs baseline: 1.0255x; 1.0255x over previous
//
#include <hip/hip_runtime.h>
#include <hip/hip_bf16.h>
#include <stdint.h>

// MoTEmbed: out[t,:] = W_{type(t)} @ h[t,:] + b_{type(t)}
// B=4, S=4096 -> T=16384 tokens, D=2048. fp32 in/out, bf16 MFMA compute.
// Round 19: straddle tile split into 32 small N=64 dual blocks appended at
// the grid tail (blockIdx 504..535). Under static block->CU assignment the
// dual no longer chains u_dual+u on one CU; triple-loaded CUs cost 2u+0.55u.
// Regular path (63 tiles x 8, R14 cadence) and prep byte-identical to R17.

#define T_TOK 16384
#define DDIM  2048
#define NT_K  32           // K tiles of 64 (regular path)
#define NT_D  64           // K tiles of 32 (dual path)
#define MT    64           // M tiles of 256 (gap-free sort)

typedef __attribute__((ext_vector_type(4))) float          f32x4;
typedef __attribute__((ext_vector_type(8))) short          bf16x8;
typedef __attribute__((ext_vector_type(2))) unsigned int   u32x2;

// ---- ws layout (bytes) ----
#define WS_HBF   0ull
#define WS_W0BF  67108864ull                 // 16384*2048*2
#define WS_W1BF  75497472ull                 // + 2048*2048*2
#define WS_META  83886080ull                 // + 2048*2048*2
#define WS_IDX   83886208ull
#define WS_NEED  (WS_IDX + 65536ull)
// meta: [0]=cur0 (final = c0) [1]=cur1

__device__ __forceinline__ unsigned short cvt1_bf16(float f) {
  unsigned u = __builtin_bit_cast(unsigned, f);
  unsigned rnd = 0x7fffu + ((u >> 16) & 1u);
  return (unsigned short)((u + rnd) >> 16);
}

__device__ __forceinline__ void gload_lds16(const void* g, void* l) {
  __builtin_amdgcn_global_load_lds(
      (const __attribute__((address_space(1))) unsigned int*)g,
      (__attribute__((address_space(3))) unsigned int*)l, 16, 0, 0);
}

#define BAR()     asm volatile("s_barrier" ::: "memory")
#define VMCNT2()  asm volatile("s_waitcnt vmcnt(2)" ::: "memory")
#define VMCNT3()  asm volatile("s_waitcnt vmcnt(3)" ::: "memory")
#define VMCNT4()  asm volatile("s_waitcnt vmcnt(4)" ::: "memory")
#define VMCNT0()  asm volatile("s_waitcnt vmcnt(0)" ::: "memory")
#define LGKM0()   asm volatile("s_waitcnt lgkmcnt(0)" ::: "memory")
#define SCHEDBAR() __builtin_amdgcn_sched_barrier(0)

// ---------- prep: fused convert(H,W0,W1) + two-sided scatter ----------
__global__ void k_prep(const float* __restrict__ H, const float* __restrict__ W0,
                       const float* __restrict__ W1, const int* __restrict__ typ,
                       unsigned short* __restrict__ Hbf,
                       unsigned short* __restrict__ W0bf,
                       unsigned short* __restrict__ W1bf,
                       int* __restrict__ meta, int* __restrict__ idx) {
  const int gid = blockIdx.x * blockDim.x + threadIdx.x;
  if (gid < T_TOK) {
    int t = typ[gid];
    int pos = (t == 0) ? atomicAdd(&meta[0], 1)
                       : (T_TOK - 1) - atomicAdd(&meta[1], 1);
    idx[pos] = gid;
  }
  const int nH = T_TOK * DDIM / 4;
  const int nW = DDIM * DDIM / 4;
  const int total = nH + 2 * nW;
  const int stride = gridDim.x * blockDim.x;
  for (int i = gid; i < total; i += stride) {
    const float* s; unsigned short* d; int j;
    if (i < nH)           { s = H;  d = Hbf;  j = i; }
    else if (i < nH + nW) { s = W0; d = W0bf; j = i - nH; }
    else                  { s = W1; d = W1bf; j = i - nH - nW; }
    f32x4 v = ((const f32x4*)s)[j];
    unsigned p0 = (unsigned)cvt1_bf16(v[0]) | ((unsigned)cvt1_bf16(v[1]) << 16);
    unsigned p1 = (unsigned)cvt1_bf16(v[2]) | ((unsigned)cvt1_bf16(v[3]) << 16);
    u32x2 o; o[0] = p0; o[1] = p1;
    ((u32x2*)d)[j] = o;
  }
}

// ---------- GEMM: 504 regular 256x256 blocks + 32 tail dual 256x64 ----------
__global__ __launch_bounds__(512) void k_gemm256(
    const unsigned short* __restrict__ Hbf,
    const unsigned short* __restrict__ W0bf,
    const unsigned short* __restrict__ W1bf,
    const float* __restrict__ B0, const float* __restrict__ B1,
    const int* __restrict__ meta, const int* __restrict__ idx,
    float* __restrict__ OUT)
{
  __shared__ char lds[131072];

  const int c0 = meta[0];
  int ms = c0 >> 8; if (ms > MT - 1) ms = MT - 1;   // straddle/boundary tile

  const int tid  = threadIdx.x;
  const int lane = tid & 63;
  const int wid  = tid >> 6;           // 0..7
  const int fr   = lane & 15;
  const int g    = lane >> 4;
  const int cs   = (lane & 3) ^ ((lane >> 3) & 3);  // pre-swizzled slot
  const int sw   = (g ^ ((fr >> 1) & 3)) << 4;      // read-side swizzle

  if (blockIdx.x < 504) {
    // ================= regular single-expert path (R14/R15 verified) ======
    // bijective XCD swizzle over 504 (chunk=63); my skips tile ms.
    const int orig = blockIdx.x;
    const int wg = (orig & 7) * 63 + (orig >> 3);
    int i_t = wg >> 3;                 // 0..62
    const int bx = wg & 7;
    const int my = i_t + (i_t >= ms ? 1 : 0);

    const int wr = wid >> 2;           // 0..1 (M half)
    const int wc = wid & 3;            // 0..3 (N quarter)
    const int start = my * 256;
    const int e0 = (start >= c0) ? 1 : 0;
    const int colBase = bx * 256;

    const char* aS[2];
    int rt[2];
#pragma unroll
    for (int l = 0; l < 2; ++l) {
      int ch = 2 * wid + l;
      rt[l] = ch * 16 + (lane >> 2);
      int orow = idx[start + rt[l]];
      aS[l] = (const char*)Hbf + (size_t)orow * 4096 + cs * 16;
    }
    const int chB = (2 * wid) * 1024;

    int aF[8], bF[4];
#pragma unroll
    for (int m = 0; m < 8; ++m) aF[m] = ((wr * 128 + m * 16 + fr) << 6) + sw;
#pragma unroll
    for (int n = 0; n < 4; ++n) bF[n] = ((wc * 64 + n * 16 + fr) << 6) + sw;

    f32x4 acc[8][4];
#pragma unroll
    for (int m = 0; m < 8; ++m)
#pragma unroll
      for (int n = 0; n < 4; ++n) acc[m][n] = (f32x4)0.0f;

    const unsigned short* Wb = e0 ? W1bf : W0bf;
    const char* wS[2];
#pragma unroll
    for (int l = 0; l < 2; ++l)
      wS[l] = (const char*)(Wb + (size_t)(colBase + rt[l]) * DDIM) + cs * 16;

    auto STAGE_A = [&](int d, int kh, int tn) {
      char* dst = lds + (d << 15) + (kh << 14) + chB;
      int ko = tn * 128 + kh * 64;
      gload_lds16(aS[0] + ko, dst);
      gload_lds16(aS[1] + ko, dst + 1024);
    };
    auto STAGE_B = [&](int d, int kh, int tn) {
      char* dst = lds + 65536 + (d << 15) + (kh << 14) + chB;
      int ko = tn * 128 + kh * 64;
      gload_lds16(wS[0] + ko, dst);
      gload_lds16(wS[1] + ko, dst + 1024);
    };

    STAGE_A(0, 0, 0); STAGE_B(0, 0, 0); STAGE_A(0, 1, 0); STAGE_B(0, 1, 0);
    VMCNT4();
    BAR();

#pragma unroll 2
    for (int t = 0; t < NT_K; ++t) {
      const int c = t & 1, d = c ^ 1;
      int t1 = t + 1; if (t1 == NT_K) t1 = NT_K - 1;
      const char* Ak0 = lds + (c << 15);
      const char* Ak1 = Ak0 + 16384;
      const char* Bk0 = lds + 65536 + (c << 15);
      const char* Bk1 = Bk0 + 16384;

      bf16x8 a[8], bb0, bb1;

      // P1: kh0 x n0-1
#pragma unroll
      for (int m = 0; m < 8; ++m) a[m] = *(const bf16x8*)(Ak0 + aF[m]);
      bb0 = *(const bf16x8*)(Bk0 + bF[0]);
      bb1 = *(const bf16x8*)(Bk0 + bF[1]);
      STAGE_A(d, 0, t1);
      BAR(); LGKM0(); SCHEDBAR();
      __builtin_amdgcn_s_setprio(1);
#pragma unroll
      for (int m = 0; m < 8; ++m) {
        acc[m][0] = __builtin_amdgcn_mfma_f32_16x16x32_bf16(a[m], bb0, acc[m][0], 0, 0, 0);
        acc[m][1] = __builtin_amdgcn_mfma_f32_16x16x32_bf16(a[m], bb1, acc[m][1], 0, 0, 0);
      }
      __builtin_amdgcn_s_setprio(0);

      // P2: kh0 x n2-3
      bb0 = *(const bf16x8*)(Bk0 + bF[2]);
      bb1 = *(const bf16x8*)(Bk0 + bF[3]);
      VMCNT2();
      STAGE_B(d, 0, t1);
      BAR(); LGKM0(); SCHEDBAR();
      __builtin_amdgcn_s_setprio(1);
#pragma unroll
      for (int m = 0; m < 8; ++m) {
        acc[m][2] = __builtin_amdgcn_mfma_f32_16x16x32_bf16(a[m], bb0, acc[m][2], 0, 0, 0);
        acc[m][3] = __builtin_amdgcn_mfma_f32_16x16x32_bf16(a[m], bb1, acc[m][3], 0, 0, 0);
      }
      __builtin_amdgcn_s_setprio(0);

      // P3: kh1 x n0-1
#pragma unroll
      for (int m = 0; m < 8; ++m) a[m] = *(const bf16x8*)(Ak1 + aF[m]);
      bb0 = *(const bf16x8*)(Bk1 + bF[0]);
      bb1 = *(const bf16x8*)(Bk1 + bF[1]);
      STAGE_A(d, 1, t1);
      BAR(); LGKM0(); SCHEDBAR();
      __builtin_amdgcn_s_setprio(1);
#pragma unroll
      for (int m = 0; m < 8; ++m) {
        acc[m][0] = __builtin_amdgcn_mfma_f32_16x16x32_bf16(a[m], bb0, acc[m][0], 0, 0, 0);
        acc[m][1] = __builtin_amdgcn_mfma_f32_16x16x32_bf16(a[m], bb1, acc[m][1], 0, 0, 0);
      }
      __builtin_amdgcn_s_setprio(0);

      // P4: kh1 x n2-3
      bb0 = *(const bf16x8*)(Bk1 + bF[2]);
      bb1 = *(const bf16x8*)(Bk1 + bF[3]);
      VMCNT2();
      STAGE_B(d, 1, t1);
      BAR(); LGKM0(); SCHEDBAR();
      __builtin_amdgcn_s_setprio(1);
#pragma unroll
      for (int m = 0; m < 8; ++m) {
        acc[m][2] = __builtin_amdgcn_mfma_f32_16x16x32_bf16(a[m], bb0, acc[m][2], 0, 0, 0);
        acc[m][3] = __builtin_amdgcn_mfma_f32_16x16x32_bf16(a[m], bb1, acc[m][3], 0, 0, 0);
      }
      __builtin_amdgcn_s_setprio(0);
    }

    VMCNT0();

    const float* Bv = e0 ? B1 : B0;
    float bias[4];
    int cols[4];
#pragma unroll
    for (int n = 0; n < 4; ++n) {
      cols[n] = colBase + wc * 64 + n * 16 + fr;
      bias[n] = Bv[cols[n]];
    }
#pragma unroll
    for (int m = 0; m < 8; ++m) {
      int lb = wr * 128 + m * 16 + (g << 2);
#pragma unroll
      for (int j = 0; j < 4; ++j) {
        int orow = idx[start + lb + j];
        float* op = OUT + (size_t)orow * DDIM;
#pragma unroll
        for (int n = 0; n < 4; ++n) op[cols[n]] = acc[m][n][j] + bias[n];
      }
    }
  } else {
    // ====== dual boundary tile: 32 blocks of 256x64, full K, BK=32 ========
    // sub = blockIdx-504: bx = sub>>2, nq = sub&3 -> colBase = bx*256+nq*64.
    // 8 waves, wave grid 4M x 2N (wave tile 64x32): acc[4][2] + accX[2].
    // LDS per buf (24KB): A 16K | B0 4K | B1 4K; dbuf = 48KB.
    // Per tile: DSTAGE(d,t+1) 3 loads; vmcnt(3) drains S(t); BAR; 8 reads;
    // lgkm0; MFMA; BAR. Census invariant 3 outstanding at entry; never
    // vmcnt(0) in loop. WAR via end-BAR of t-1.
    const int sub = blockIdx.x - 504;
    const int bx = sub >> 2;
    const int nq = sub & 3;
    const int colBase = bx * 256 + nq * 64;
    const int start = ms * 256;

    const int wr = wid >> 1;           // 0..3 (64-row band)
    const int wc = wid & 1;            // 0..1 (32-col half)

    // A staging sources (16 chunks of 16 rows; wave stages 2)
    const char* aS[2];
#pragma unroll
    for (int l = 0; l < 2; ++l) {
      int r_t = (2 * wid + l) * 16 + (lane >> 2);
      int orow = idx[start + r_t];
      aS[l] = (const char*)Hbf + (size_t)orow * 4096 + cs * 16;
    }
    // B staging source: waves 0-3 -> B0 chunk wid; waves 4-7 -> B1 chunk wid-4
    const unsigned short* Wbs = (wid < 4) ? W0bf : W1bf;
    const int bchunk = wid & 3;
    const char* bS = (const char*)(Wbs + (size_t)(colBase + bchunk * 16 + (lane >> 2)) * DDIM) + cs * 16;

    // fragment offsets
    int aF[4], bF[2];
#pragma unroll
    for (int m = 0; m < 4; ++m) aF[m] = ((wr * 64 + m * 16 + fr) << 6) + sw;
#pragma unroll
    for (int n = 0; n < 2; ++n) bF[n] = ((wc * 32 + n * 16 + fr) << 6) + sw;

    const int lo_w = c0 - start - wr * 64;       // wave-uniform
    int mmix = 8;
    if (lo_w > 0 && lo_w < 64 && (lo_w & 15)) mmix = lo_w >> 4;

    f32x4 acc[4][2], accX[2];
#pragma unroll
    for (int m = 0; m < 4; ++m) { acc[m][0] = (f32x4)0.0f; acc[m][1] = (f32x4)0.0f; }
    accX[0] = (f32x4)0.0f; accX[1] = (f32x4)0.0f;

    auto DSTAGE = [&](int d, int tn) {
      int ko = tn * 64;
      char* ad = lds + d * 24576;
      gload_lds16(aS[0] + ko, ad + (2 * wid) * 1024);
      gload_lds16(aS[1] + ko, ad + (2 * wid + 1) * 1024);
      char* bd = ad + 16384 + (wid < 4 ? 0 : 4096) + bchunk * 1024;
      gload_lds16(bS + ko, bd);
    };

    DSTAGE(0, 0);
    VMCNT0();
    BAR();

    for (int t = 0; t < NT_D; ++t) {
      const int c = t & 1, d = c ^ 1;
      int t1 = t + 1; if (t1 == NT_D) t1 = NT_D - 1;
      DSTAGE(d, t1);
      VMCNT3();                        // drains S(t) (no-op at t=0)
      BAR();
      const char* Ac  = lds + c * 24576;
      const char* B0c = Ac + 16384;
      const char* B1c = Ac + 20480;
      bf16x8 a[4], b0f[2], b1f[2];
#pragma unroll
      for (int m = 0; m < 4; ++m) a[m] = *(const bf16x8*)(Ac + aF[m]);
#pragma unroll
      for (int n = 0; n < 2; ++n) {
        b0f[n] = *(const bf16x8*)(B0c + bF[n]);
        b1f[n] = *(const bf16x8*)(B1c + bF[n]);
      }
      LGKM0(); SCHEDBAR();
      __builtin_amdgcn_s_setprio(1);
#pragma unroll
      for (int m = 0; m < 4; ++m) {
        if (m == mmix) {
#pragma unroll
          for (int n = 0; n < 2; ++n) {
            acc[m][n] = __builtin_amdgcn_mfma_f32_16x16x32_bf16(a[m], b0f[n], acc[m][n], 0, 0, 0);
            accX[n]   = __builtin_amdgcn_mfma_f32_16x16x32_bf16(a[m], b1f[n], accX[n],   0, 0, 0);
          }
        } else if (m * 16 >= lo_w) {
#pragma unroll
          for (int n = 0; n < 2; ++n)
            acc[m][n] = __builtin_amdgcn_mfma_f32_16x16x32_bf16(a[m], b1f[n], acc[m][n], 0, 0, 0);
        } else {
#pragma unroll
          for (int n = 0; n < 2; ++n)
            acc[m][n] = __builtin_amdgcn_mfma_f32_16x16x32_bf16(a[m], b0f[n], acc[m][n], 0, 0, 0);
        }
      }
      __builtin_amdgcn_s_setprio(0);
      BAR();                           // reads of buf c done -> WAR-safe
    }
    VMCNT0();

    int cols[2];
    float bias0v[2], bias1v[2];
#pragma unroll
    for (int n = 0; n < 2; ++n) {
      cols[n] = colBase + wc * 32 + n * 16 + fr;
      bias0v[n] = B0[cols[n]];
      bias1v[n] = B1[cols[n]];
    }
#pragma unroll
    for (int m = 0; m < 4; ++m) {
#pragma unroll
      for (int j = 0; j < 4; ++j) {
        int p = start + wr * 64 + m * 16 + (g << 2) + j;
        int orow = idx[p];
        float* op = OUT + (size_t)orow * DDIM;
        int e1r = (p >= c0) ? 1 : 0;
        if (m == mmix && e1r) {
#pragma unroll
          for (int n = 0; n < 2; ++n) op[cols[n]] = accX[n][j] + bias1v[n];
        } else {
#pragma unroll
          for (int n = 0; n < 2; ++n)
            op[cols[n]] = acc[m][n][j] + (e1r ? bias1v[n] : bias0v[n]);
        }
      }
    }
  }
}

// ---------- fallback: verified round-4 kernel ----------
#define BMd 64
#define BNd 64
#define BKd 32
#define LDW 36

__device__ __forceinline__ bf16x8 cvt_bf16x8(f32x4 lo, f32x4 hi) {
  bf16x8 r;
#pragma unroll
  for (int i = 0; i < 4; ++i) {
    r[i]     = (short)cvt1_bf16(lo[i]);
    r[i + 4] = (short)cvt1_bf16(hi[i]);
  }
  return r;
}

__global__ __launch_bounds__(256, 2) void mot_mfma_diag(
    const float* __restrict__ H,  const int* __restrict__ TYP,
    const float* __restrict__ W0, const float* __restrict__ B0,
    const float* __restrict__ W1, const float* __restrict__ B1,
    float* __restrict__ OUT)
{
  __shared__ float As[BMd * LDW];
  __shared__ float W0s[BNd * LDW];
  __shared__ float W1s[BNd * LDW];

  const int tid = threadIdx.x;
  const int rowBase = blockIdx.y * BMd;
  const int colBase = blockIdx.x * BNd;
  const int srow  = tid >> 3;
  const int scol4 = (tid & 7) << 2;
  const float* hA  = H  + (size_t)(rowBase + srow) * DDIM + scol4;
  const float* hW0 = W0 + (size_t)(colBase + srow) * DDIM + scol4;
  const float* hW1 = W1 + (size_t)(colBase + srow) * DDIM + scol4;

  const int lane = tid & 63;
  const int w    = tid >> 6;
  const int fr   = lane & 15;
  const int g    = lane >> 4;

  f32x4 acc0[4], acc1[4];
#pragma unroll
  for (int m = 0; m < 4; ++m) { acc0[m] = (f32x4)0.0f; acc1[m] = (f32x4)0.0f; }

  for (int k0 = 0; k0 < DDIM; k0 += BKd) {
    f32x4 va[2], v0[2], v1[2];
#pragma unroll
    for (int p = 0; p < 2; ++p) {
      va[p] = *(const f32x4*)(hA  + (size_t)p * 32 * DDIM);
      v0[p] = *(const f32x4*)(hW0 + (size_t)p * 32 * DDIM);
      v1[p] = *(const f32x4*)(hW1 + (size_t)p * 32 * DDIM);
    }
    hA += BKd; hW0 += BKd; hW1 += BKd;
    __syncthreads();
#pragma unroll
    for (int p = 0; p < 2; ++p) {
      int r = srow + 32 * p;
      *(f32x4*)(&As [r * LDW + scol4]) = va[p];
      *(f32x4*)(&W0s[r * LDW + scol4]) = v0[p];
      *(f32x4*)(&W1s[r * LDW + scol4]) = v1[p];
    }
    __syncthreads();

    bf16x8 af[4];
#pragma unroll
    for (int m = 0; m < 4; ++m) {
      const float* ap = &As[(m * 16 + fr) * LDW + g * 8];
      af[m] = cvt_bf16x8(*(const f32x4*)ap, *(const f32x4*)(ap + 4));
    }
    const float* b0p = &W0s[(w * 16 + fr) * LDW + g * 8];
    const float* b1p = &W1s[(w * 16 + fr) * LDW + g * 8];
    bf16x8 bf0 = cvt_bf16x8(*(const f32x4*)b0p, *(const f32x4*)(b0p + 4));
    bf16x8 bf1 = cvt_bf16x8(*(const f32x4*)b1p, *(const f32x4*)(b1p + 4));
#pragma unroll
    for (int m = 0; m < 4; ++m) {
      acc0[m] = __builtin_amdgcn_mfma_f32_16x16x32_bf16(af[m], bf0, acc0[m], 0, 0, 0);
      acc1[m] = __builtin_amdgcn_mfma_f32_16x16x32_bf16(af[m], bf1, acc1[m], 0, 0, 0);
    }
  }

  const int col = colBase + w * 16 + fr;
  const float bz0 = B0[col];
  const float bz1 = B1[col];
#pragma unroll
  for (int m = 0; m < 4; ++m)
#pragma unroll
    for (int j = 0; j < 4; ++j) {
      int row = rowBase + m * 16 + (g << 2) + j;
      int t = TYP[row];
      OUT[(size_t)row * DDIM + col] = (t == 0) ? (acc0[m][j] + bz0) : (acc1[m][j] + bz1);
    }
}

extern "C" void kernel_launch(void* const* d_in, const int* in_sizes, int n_in,
                              void* d_out, int out_size, void* d_ws, size_t ws_size,
                              hipStream_t stream) {
  const float* H   = (const float*)d_in[0];
  const int*   TYP = (const int*)  d_in[1];
  const float* W0  = (const float*)d_in[2];
  const float* B0v = (const float*)d_in[3];
  const float* W1  = (const float*)d_in[4];
  const float* B1v = (const float*)d_in[5];
  float* OUT = (float*)d_out;

  if (ws_size < WS_NEED) {
    dim3 grid(DDIM / BNd, T_TOK / BMd);
    mot_mfma_diag<<<grid, dim3(256), 0, stream>>>(H, TYP, W0, B0v, W1, B1v, OUT);
    return;
  }

  unsigned short* Hbf  = (unsigned short*)((char*)d_ws + WS_HBF);
  unsigned short* W0bf = (unsigned short*)((char*)d_ws + WS_W0BF);
  unsigned short* W1bf = (unsigned short*)((char*)d_ws + WS_W1BF);
  int* meta = (int*)((char*)d_ws + WS_META);
  int* idx  = (int*)((char*)d_ws + WS_IDX);

  hipMemsetAsync(meta, 0, 16, stream);
  k_prep<<<4096, 256, 0, stream>>>(H, W0, W1, TYP, Hbf, W0bf, W1bf, meta, idx);
  k_gemm256<<<536, 512, 0, stream>>>(Hbf, W0bf, W1bf, B0v, B1v, meta, idx, OUT);
}